// Round 10
// baseline (109.354 us; speedup 1.0000x reference)
//
#include <hip/hip_runtime.h>

#define B_ 8
#define C_ 256
#define N_ 2048
#define D_ 256
#define KKEEP 1843      // round(2048 * 0.9)
#define LEAKY 0.01f
#define EPS 1e-5f

using short8  = __attribute__((ext_vector_type(8))) short;
using ushort8 = __attribute__((ext_vector_type(8))) unsigned short;
using ushort4v = __attribute__((ext_vector_type(4))) unsigned short;
using f32x4   = __attribute__((ext_vector_type(4))) float;

__device__ inline unsigned short f2bf(float x) {          // RNE f32->bf16
  unsigned u = __float_as_uint(x);
  u += 0x7fffu + ((u >> 16) & 1u);
  return (unsigned short)(u >> 16);
}
__device__ inline float bf2f(unsigned short u) { return __uint_as_float(((unsigned)u) << 16); }

// async global -> LDS, 16B per lane. LDS dest is wave-uniform base + lane*16.
__device__ inline void gload16(const void* g, void* l) {
  __builtin_amdgcn_global_load_lds(
      (const __attribute__((address_space(1))) void*)g,
      (__attribute__((address_space(3))) void*)l, 16, 0, 0);
}

// ---------- transpose + cast: src (rows x cols) fp32 -> dst (cols x rows) bf16
// PIN: 1-D grid, b = lin&7 -> XCD b (batch locality for downstream GEMMs).
template<bool PIN>
__global__ __launch_bounds__(256) void k_transpose_cast(const float* __restrict__ src,
                                                        unsigned short* __restrict__ dst,
                                                        int rows, int cols, int njt,
                                                        size_t srcBatch, size_t dstBatch) {
  __shared__ float tile[32][33];
  int b, i0, j0;
  if constexpr (PIN) {
    int lin = blockIdx.x;
    b = lin & 7;
    int rest = lin >> 3;
    j0 = (rest % njt) * 32;
    i0 = (rest / njt) * 32;
  } else {
    b = blockIdx.z; j0 = blockIdx.x * 32; i0 = blockIdx.y * 32;
  }
  src += (size_t)b * srcBatch;
  dst += (size_t)b * dstBatch;
  int t = threadIdx.x;
  int tc = t & 31, tr = t >> 5;
#pragma unroll
  for (int k = 0; k < 4; ++k)
    tile[tr + k * 8][tc] = src[(size_t)(i0 + tr + k * 8) * cols + j0 + tc];
  __syncthreads();
  int r2 = t >> 3, q = t & 7;                 // write row j0+r2, 4 consecutive c
  ushort4v v;
#pragma unroll
  for (int l = 0; l < 4; ++l) v[l] = f2bf(tile[q * 4 + l][r2]);
  *(ushort4v*)&dst[(size_t)(j0 + r2) * rows + i0 + q * 4] = v;
}

// ---------- NT MFMA GEMM (support + gram): C[i][j] = sum_k A[i][k]*Bt[j][k]
// 128x128 tile, BK=64, global_load_lds staging (linear LDS), XOR-swizzled
// source + read (T2, both-sides). batch->XCD pinned 1-D grid.
template<int K_, int NX>
__global__ __launch_bounds__(256) void k_gemm(const short* __restrict__ A,
                                              const short* __restrict__ Bt,
                                              unsigned short* __restrict__ Cout,
                                              size_t aStride, size_t bStride, size_t cStride,
                                              int ldc) {
  __shared__ short As[128][64];   // linear; swizzle handled in addresses
  __shared__ short Bs[128][64];
  int lin = blockIdx.x;
  int b = lin & 7;                 // XCD id == batch
  int rest = lin >> 3;
  int bxi = rest % NX, byi = rest / NX;
  const short* Ab = A + (size_t)b * aStride;
  const short* Bb = Bt + (size_t)b * bStride;
  int bi = byi * 128, bj = bxi * 128;
  int t = threadIdx.x, lane = t & 63, wid = t >> 6;
  int wr = (wid >> 1) * 64, wc = (wid & 1) * 64;
  int fr = lane & 15;
  int wbase = wid * 512;           // wave-uniform LDS offset (shorts) per issue

  f32x4 acc[4][4];
  f32x4 z = {0.f, 0.f, 0.f, 0.f};
#pragma unroll
  for (int i = 0; i < 4; ++i)
#pragma unroll
    for (int j = 0; j < 4; ++j) acc[i][j] = z;

  for (int c0 = 0; c0 < K_; c0 += 64) {
    if (c0) __syncthreads();       // previous compute done before overwrite
#pragma unroll
    for (int i = 0; i < 4; ++i) {
      int li = i * 256 + t;
      int row = li >> 3, ch = li & 7;
      int sw = ((ch ^ (row & 7)) << 3);          // pre-swizzled source chunk
      gload16(Ab + (size_t)(bi + row) * K_ + c0 + sw, (short*)As + i * 2048 + wbase);
      gload16(Bb + (size_t)(bj + row) * K_ + c0 + sw, (short*)Bs + i * 2048 + wbase);
    }
    __syncthreads();               // vmcnt(0) drain + barrier
#pragma unroll
    for (int ksub = 0; ksub < 2; ++ksub) {
      int cA = ksub * 4 + (lane >> 4);           // logical 16B chunk 0..7
      short8 af[4], bf[4];
#pragma unroll
      for (int f = 0; f < 4; ++f) {
        int R = wr + f * 16 + fr;
        af[f] = *(const short8*)&As[R][(cA ^ (R & 7)) << 3];
        int Rb = wc + f * 16 + fr;
        bf[f] = *(const short8*)&Bs[Rb][(cA ^ (Rb & 7)) << 3];
      }
#pragma unroll
      for (int fi = 0; fi < 4; ++fi)
#pragma unroll
        for (int fj = 0; fj < 4; ++fj)
          acc[fi][fj] = __builtin_amdgcn_mfma_f32_16x16x32_bf16(af[fi], bf[fj], acc[fi][fj], 0, 0, 0);
    }
  }

  // epilogue: C/D layout: col = lane&15, row = (lane>>4)*4 + reg
  int orow = (lane >> 4) * 4;
  int ocol = lane & 15;
#pragma unroll
  for (int fi = 0; fi < 4; ++fi)
#pragma unroll
    for (int fj = 0; fj < 4; ++fj)
#pragma unroll
      for (int r = 0; r < 4; ++r) {
        size_t idx = (size_t)b * cStride +
                     (size_t)(bi + wr + fi * 16 + orow + r) * ldc +
                     (size_t)(bj + wc + fj * 16 + ocol);
        Cout[idx] = f2bf(acc[fi][fj][r]);
      }
}

// ---------- softmax + exact(bf16-granularity) top-k threshold + mask, one WAVE
// per row; batch->XCD pinned so S[b] L2 locality chains gram -> softmax -> PV.
__global__ __launch_bounds__(256) void k_softmax_topk(unsigned short* __restrict__ S) {
  int t = threadIdx.x;
  int lane = t & 63, wv = t >> 6;
  int lin = blockIdx.x;
  int b = lin & 7;
  int grp = lin >> 3;              // 512 groups of 4 rows per batch
  size_t row = (size_t)b * N_ + grp * 4 + wv;
  unsigned short* sr = S + row * N_;

  float e[32];
#pragma unroll
  for (int i = 0; i < 4; ++i) {
    ushort8 raw = *(const ushort8*)(sr + ((size_t)(i * 64 + lane)) * 8);
#pragma unroll
    for (int j = 0; j < 8; ++j) e[i * 8 + j] = bf2f(raw[j]);
  }

  float lm = e[0];
#pragma unroll
  for (int j = 1; j < 32; ++j) lm = fmaxf(lm, e[j]);
#pragma unroll
  for (int m = 1; m <= 16; m <<= 1) lm = fmaxf(lm, __shfl_xor(lm, m));
  lm = fmaxf(__shfl(lm, 0), __shfl(lm, 32));

  float ls = 0.f;
#pragma unroll
  for (int j = 0; j < 32; ++j) { e[j] = __expf(e[j] - lm); ls += e[j]; }
#pragma unroll
  for (int m = 1; m <= 16; m <<= 1) ls += __shfl_xor(ls, m);
  ls = __shfl(ls, 0) + __shfl(ls, 32);
  float inv = 1.0f / ls;

  unsigned kp[16], vo[16];
#pragma unroll
  for (int q = 0; q < 16; ++q)
    kp[q] = (unsigned)f2bf(e[q]) | ((unsigned)f2bf(e[q + 16]) << 16);
#pragma unroll
  for (int q = 0; q < 16; ++q)
    vo[q] = (unsigned)f2bf(e[2 * q] * inv) | ((unsigned)f2bf(e[2 * q + 1] * inv) << 16);

  unsigned tp[16];
#pragma unroll
  for (int q = 0; q < 16; ++q) tp[q] = kp[q];
#pragma unroll
  for (int sI = 0; sI < 4; ++sI) {
    const int s = 8 >> sI;
    const unsigned msk = (s == 8) ? 0x00FF00FFu : (s == 4) ? 0x0F0F0F0Fu
                       : (s == 2) ? 0x33333333u : 0x55555555u;
#pragma unroll
    for (int k = 0; k < 16; ++k) {
      if ((k & s) == 0) {
        unsigned tt = ((tp[k] >> s) ^ tp[k + s]) & msk;
        tp[k + s] ^= tt;
        tp[k]     ^= tt << s;
      }
    }
  }

  unsigned alive = 0xFFFFFFFFu, prefix = 0u;
  int need = KKEEP;
#pragma unroll
  for (int b2 = 12; b2 >= 0; b2 -= 2) {
    unsigned p1 = tp[b2 + 1], p0 = tp[b2];
    unsigned hi = alive & p1;
    unsigned m3 = hi & p0, m2 = hi & ~p0, m1v = (alive & ~p1) & p0;
    unsigned packed = (unsigned)__popc(m3) | ((unsigned)__popc(m2) << 11) |
                      ((unsigned)__popc(m1v) << 22);
#pragma unroll
    for (int m = 1; m <= 16; m <<= 1) packed += __shfl_xor(packed, m);
    unsigned v0 = __shfl(packed, 0), v32 = __shfl(packed, 32);
    int C3 = (int)((v0 & 0x7FFu) + (v32 & 0x7FFu));
    int C2 = (int)(((v0 >> 11) & 0x7FFu) + ((v32 >> 11) & 0x7FFu));
    int C1 = (int)(((v0 >> 22) & 0x7FFu) + ((v32 >> 22) & 0x7FFu));
    int cum2 = C3 + C2, cum1 = cum2 + C1;
    if (C3 >= need)        { alive = m3;  prefix |= 3u << b2; }
    else if (cum2 >= need) { alive = m2;  prefix |= 2u << b2; need -= C3; }
    else if (cum1 >= need) { alive = m1v; prefix |= 1u << b2; need -= cum2; }
    else                   { alive ^= (m3 | m2 | m1v);        need -= cum1; }
  }

#pragma unroll
  for (int i = 0; i < 4; ++i) {
    ushort8 o;
#pragma unroll
    for (int j = 0; j < 8; ++j) {
      int idx = i * 8 + j;
      unsigned key = (kp[idx & 15] >> ((idx >> 4) * 16)) & 0xFFFFu;
      unsigned val = (vo[idx >> 1] >> ((idx & 1) * 16)) & 0xFFFFu;
      o[j] = (key >= prefix) ? (unsigned short)val : (unsigned short)0;
    }
    *(ushort8*)(sr + ((size_t)(i * 64 + lane)) * 8) = o;
  }
}

// ---------- PV GEMM: pre(n,d) = P . supT^T, 128x64 tile, BK=64, 8 WAVES,
// global_load_lds + XOR swizzle; leaky + bf16 out + fused BN partials.
__global__ __launch_bounds__(512) void k_pv(const short* __restrict__ A,   // masked P bf16
                                            const short* __restrict__ Bt,  // supT
                                            unsigned short* __restrict__ pre,
                                            float* __restrict__ ps, float* __restrict__ pss) {
  __shared__ short As[128][64];
  __shared__ short Bs[64][64];
  int lin = blockIdx.x;
  int b = lin & 7;                 // batch -> XCD
  int rest = lin >> 3;
  int bxi = rest & 3;              // nx = 4
  int byi = rest >> 2;
  const short* Ab = A + (size_t)b * N_ * N_;
  const short* Bb = Bt + (size_t)b * D_ * N_;
  int bi = byi * 128, bj = bxi * 64;
  int t = threadIdx.x, lane = t & 63, w = t >> 6;   // 8 waves
  int wr = (w >> 1) * 32, wc = (w & 1) * 32;        // wave tile 32x32
  int fr = lane & 15;

  f32x4 acc[2][2];
  f32x4 z = {0.f, 0.f, 0.f, 0.f};
#pragma unroll
  for (int i = 0; i < 2; ++i)
#pragma unroll
    for (int j = 0; j < 2; ++j) acc[i][j] = z;

  for (int c0 = 0; c0 < N_; c0 += 64) {
    if (c0) __syncthreads();
    {
      // As: 2 issues of 512 lanes (rows 0..63, 64..127); Bs: 1 issue
      int row = t >> 3, ch = t & 7;
      int sw = ((ch ^ (row & 7)) << 3);
      gload16(Ab + (size_t)(bi + row) * N_ + c0 + sw, (short*)As + w * 512);
      gload16(Bb + (size_t)(bj + row) * N_ + c0 + sw, (short*)Bs + w * 512);
      int li = 512 + t;
      int row1 = li >> 3, ch1 = li & 7;
      int sw1 = ((ch1 ^ (row1 & 7)) << 3);
      gload16(Ab + (size_t)(bi + row1) * N_ + c0 + sw1, (short*)As + 4096 + w * 512);
    }
    __syncthreads();
#pragma unroll
    for (int ksub = 0; ksub < 2; ++ksub) {
      int cA = ksub * 4 + (lane >> 4);
      short8 af[2], bf[2];
#pragma unroll
      for (int f = 0; f < 2; ++f) {
        int R = wr + f * 16 + fr;
        af[f] = *(const short8*)&As[R][(cA ^ (R & 7)) << 3];
        int Rb = wc + f * 16 + fr;
        bf[f] = *(const short8*)&Bs[Rb][(cA ^ (Rb & 7)) << 3];
      }
#pragma unroll
      for (int fi = 0; fi < 2; ++fi)
#pragma unroll
        for (int fj = 0; fj < 2; ++fj)
          acc[fi][fj] = __builtin_amdgcn_mfma_f32_16x16x32_bf16(af[fi], bf[fj], acc[fi][fj], 0, 0, 0);
    }
  }

  // epilogue: leaky + bf16 store + per-channel partial sums
  int orow = (lane >> 4) * 4;
  int ocol = lane & 15;
  float s2[2] = {0.f, 0.f}, ss2[2] = {0.f, 0.f};
#pragma unroll
  for (int fi = 0; fi < 2; ++fi)
#pragma unroll
    for (int rr = 0; rr < 4; ++rr) {
      int rowg = bi + wr + fi * 16 + orow + rr;
      size_t base = ((size_t)b * N_ + rowg) * D_ + bj;
#pragma unroll
      for (int fj = 0; fj < 2; ++fj) {
        float v = acc[fi][fj][rr];
        v = (v >= 0.f) ? v : LEAKY * v;
        pre[base + wc + fj * 16 + ocol] = f2bf(v);
        s2[fj] += v;
        ss2[fj] = fmaf(v, v, ss2[fj]);
      }
    }
#pragma unroll
  for (int fj = 0; fj < 2; ++fj) {
    s2[fj] += __shfl_xor(s2[fj], 16);  s2[fj] += __shfl_xor(s2[fj], 32);
    ss2[fj] += __shfl_xor(ss2[fj], 16); ss2[fj] += __shfl_xor(ss2[fj], 32);
  }
  __syncthreads();
  float* sred = (float*)As;               // reuse LDS: [w][fj][16] x {s,ss}
  if (lane < 16) {
#pragma unroll
    for (int fj = 0; fj < 2; ++fj) {
      sred[(w * 2 + fj) * 16 + lane] = s2[fj];
      sred[256 + (w * 2 + fj) * 16 + lane] = ss2[fj];
    }
  }
  __syncthreads();
  if (t < 64) {
    int cw = t >> 5, fj = (t >> 4) & 1, oc = t & 15;
    float s = 0.f, ss = 0.f;
#pragma unroll
    for (int rw = 0; rw < 4; ++rw) {
      int w2 = rw * 2 + cw;
      s  += sred[(w2 * 2 + fj) * 16 + oc];
      ss += sred[256 + (w2 * 2 + fj) * 16 + oc];
    }
    ps[(size_t)lin * 64 + t] = s;
    pss[(size_t)lin * 64 + t] = ss;
  }
}

// ---------- BN finalize: 4 blocks x 64 channels
__global__ void k_final(const float* __restrict__ ps, const float* __restrict__ pss,
                        const float* __restrict__ bnw, const float* __restrict__ bnb,
                        float* __restrict__ scale, float* __restrict__ shift) {
  int col = threadIdx.x;            // 64
  int bxi = blockIdx.x;             // 4
  int ch = bxi * 64 + col;
  float s = 0.f, ss = 0.f;
  for (int byi = 0; byi < 16; ++byi)
    for (int bb = 0; bb < 8; ++bb) {
      int lin = (byi * 4 + bxi) * 8 + bb;
      s += ps[(size_t)lin * 64 + col];
      ss += pss[(size_t)lin * 64 + col];
    }
  const float invN = 1.0f / (B_ * N_);
  float mean = s * invN;
  float var = fmaf(-mean, mean, ss * invN);
  float istd = rsqrtf(var + EPS);
  float sc = istd * bnw[ch];
  scale[ch] = sc;
  shift[ch] = fmaf(-mean, sc, bnb[ch]);
}

// ---------- normalize + transpose (b,n,d) bf16 -> (b,d,n) f32; batch-pinned
__global__ __launch_bounds__(256) void k_out(const unsigned short* __restrict__ pre,
                                             const float* __restrict__ scale,
                                             const float* __restrict__ shift,
                                             float* __restrict__ out) {
  __shared__ float tile[32][33];
  int lin = blockIdx.x;
  int b = lin & 7;
  int rest = lin >> 3;
  int d0 = (rest & 7) * 32;
  int n0 = (rest >> 3) * 32;
  int tc = threadIdx.x & 31;
  int tr = threadIdx.x >> 5;
  const unsigned short* pb = pre + ((size_t)b * N_ + n0) * D_ + d0;
#pragma unroll
  for (int i = 0; i < 4; ++i) {
    int r = tr + i * 8;
    tile[r][tc] = bf2f(pb[(size_t)r * D_ + tc]);
  }
  __syncthreads();
  float* ob = out + ((size_t)b * D_ + d0) * N_ + n0;
#pragma unroll
  for (int i = 0; i < 4; ++i) {
    int r = tr + i * 8;
    float vv = tile[tc][r];
    ob[(size_t)r * N_ + tc] = fmaf(vv, scale[d0 + r], shift[d0 + r]);
  }
}

extern "C" void kernel_launch(void* const* d_in, const int* in_sizes, int n_in,
                              void* d_out, int out_size, void* d_ws, size_t ws_size,
                              hipStream_t stream) {
  const float* x = (const float*)d_in[0];
  const float* W = (const float*)d_in[1];
  const float* bnw = (const float*)d_in[2];
  const float* bnb = (const float*)d_in[3];
  float* out = (float*)d_out;

  char* w = (char*)d_ws;
  short* xt = (short*)w;            w += (size_t)B_ * N_ * C_ * 2;     // (b,n,c) bf16
  short* wt = (short*)w;            w += (size_t)D_ * C_ * 2;          // (d,c) bf16
  short* supT = (short*)w;          w += (size_t)B_ * D_ * N_ * 2;     // (b,d,m) bf16
  short* S = (short*)w;             w += (size_t)B_ * N_ * N_ * 2;     // (b,n,m) bf16
  unsigned short* pre = (unsigned short*)w; w += (size_t)B_ * N_ * D_ * 2; // (b,n,d) bf16
  float* ps = (float*)w;            w += (size_t)512 * 64 * 4;         // stat partials
  float* pss = (float*)w;           w += (size_t)512 * 64 * 4;
  float* scale = (float*)w;         w += D_ * 4;
  float* shift = (float*)w;         w += D_ * 4;

  // 1. layout prep (x pinned by batch; W has no batch)
  k_transpose_cast<true><<<dim3(8 * 64 * 8, 1, 1), 256, 0, stream>>>(
      x, (unsigned short*)xt, C_, N_, 64, (size_t)C_ * N_, (size_t)N_ * C_);
  k_transpose_cast<false><<<dim3(D_ / 32, C_ / 32, 1), 256, 0, stream>>>(
      W, (unsigned short*)wt, C_, D_, 0, 0, 0);

  // 2. supT(d,m) = wt . xt^T  (M=256, cols=2048) — 256 blocks, batch->XCD pinned
  k_gemm<C_, 16><<<dim3(8 * 16 * 2, 1, 1), 256, 0, stream>>>(
      wt, xt, (unsigned short*)supT, 0, (size_t)N_ * C_, (size_t)D_ * N_, N_);

  // 3. S(n,m) = xt . xt^T — 2048 blocks, batch->XCD pinned
  k_gemm<C_, 16><<<dim3(8 * 16 * 16, 1, 1), 256, 0, stream>>>(
      xt, xt, (unsigned short*)S, (size_t)N_ * C_, (size_t)N_ * C_, (size_t)N_ * N_, N_);

  // 4. softmax + topk mask (in place), one wave per row, batch->XCD pinned
  k_softmax_topk<<<B_ * N_ / 4, 256, 0, stream>>>((unsigned short*)S);

  // 5. PV (BK=64, gload_lds, 8 waves), leaky + bf16 out + fused BN partials
  k_pv<<<dim3(4 * 16 * 8, 1, 1), 512, 0, stream>>>(S, supT, pre, ps, pss);

  // 6. finalize BN + output (batch-pinned)
  k_final<<<4, 64, 0, stream>>>(ps, pss, bnw, bnb, scale, shift);
  k_out<<<B_ * (N_ / 32) * (D_ / 32), 256, 0, stream>>>(pre, scale, shift, out);
}

// Round 11
// 107.864 us; speedup vs baseline: 1.0138x; 1.0138x over previous
//
#include <hip/hip_runtime.h>

#define B_ 8
#define C_ 256
#define N_ 2048
#define D_ 256
#define KKEEP 1843      // round(2048 * 0.9)
#define LEAKY 0.01f
#define EPS 1e-5f

using short8  = __attribute__((ext_vector_type(8))) short;
using ushort8 = __attribute__((ext_vector_type(8))) unsigned short;
using ushort4v = __attribute__((ext_vector_type(4))) unsigned short;
using f32x4   = __attribute__((ext_vector_type(4))) float;

__device__ inline unsigned short f2bf(float x) {          // RNE f32->bf16
  unsigned u = __float_as_uint(x);
  u += 0x7fffu + ((u >> 16) & 1u);
  return (unsigned short)(u >> 16);
}
__device__ inline float bf2f(unsigned short u) { return __uint_as_float(((unsigned)u) << 16); }

// async global -> LDS, 16B per lane. LDS dest is wave-uniform base + lane*16.
__device__ inline void gload16(const void* g, void* l) {
  __builtin_amdgcn_global_load_lds(
      (const __attribute__((address_space(1))) void*)g,
      (__attribute__((address_space(3))) void*)l, 16, 0, 0);
}

// ---------- transpose + cast: src (rows x cols) fp32 -> dst (cols x rows) bf16
template<bool PIN>
__global__ __launch_bounds__(256) void k_transpose_cast(const float* __restrict__ src,
                                                        unsigned short* __restrict__ dst,
                                                        int rows, int cols, int njt,
                                                        size_t srcBatch, size_t dstBatch) {
  __shared__ float tile[32][33];
  int b, i0, j0;
  if constexpr (PIN) {
    int lin = blockIdx.x;
    b = lin & 7;
    int rest = lin >> 3;
    j0 = (rest % njt) * 32;
    i0 = (rest / njt) * 32;
  } else {
    b = blockIdx.z; j0 = blockIdx.x * 32; i0 = blockIdx.y * 32;
  }
  src += (size_t)b * srcBatch;
  dst += (size_t)b * dstBatch;
  int t = threadIdx.x;
  int tc = t & 31, tr = t >> 5;
#pragma unroll
  for (int k = 0; k < 4; ++k)
    tile[tr + k * 8][tc] = src[(size_t)(i0 + tr + k * 8) * cols + j0 + tc];
  __syncthreads();
  int r2 = t >> 3, q = t & 7;
  ushort4v v;
#pragma unroll
  for (int l = 0; l < 4; ++l) v[l] = f2bf(tile[q * 4 + l][r2]);
  *(ushort4v*)&dst[(size_t)(j0 + r2) * rows + i0 + q * 4] = v;
}

// ---------- NT MFMA GEMM (support): C[i][j] = sum_k A[i][k]*Bt[j][k]
// 128x128 tile, BK=64, gload_lds staging, both-sides XOR swizzle, batch->XCD pin.
template<int K_, int NX>
__global__ __launch_bounds__(256) void k_gemm(const short* __restrict__ A,
                                              const short* __restrict__ Bt,
                                              unsigned short* __restrict__ Cout,
                                              size_t aStride, size_t bStride, size_t cStride,
                                              int ldc) {
  __shared__ short As[128][64];
  __shared__ short Bs[128][64];
  int lin = blockIdx.x;
  int b = lin & 7;
  int rest = lin >> 3;
  int bxi = rest % NX, byi = rest / NX;
  const short* Ab = A + (size_t)b * aStride;
  const short* Bb = Bt + (size_t)b * bStride;
  int bi = byi * 128, bj = bxi * 128;
  int t = threadIdx.x, lane = t & 63, wid = t >> 6;
  int wr = (wid >> 1) * 64, wc = (wid & 1) * 64;
  int fr = lane & 15;
  int wbase = wid * 512;

  f32x4 acc[4][4];
  f32x4 z = {0.f, 0.f, 0.f, 0.f};
#pragma unroll
  for (int i = 0; i < 4; ++i)
#pragma unroll
    for (int j = 0; j < 4; ++j) acc[i][j] = z;

  for (int c0 = 0; c0 < K_; c0 += 64) {
    if (c0) __syncthreads();
#pragma unroll
    for (int i = 0; i < 4; ++i) {
      int li = i * 256 + t;
      int row = li >> 3, ch = li & 7;
      int sw = ((ch ^ (row & 7)) << 3);
      gload16(Ab + (size_t)(bi + row) * K_ + c0 + sw, (short*)As + i * 2048 + wbase);
      gload16(Bb + (size_t)(bj + row) * K_ + c0 + sw, (short*)Bs + i * 2048 + wbase);
    }
    __syncthreads();
#pragma unroll
    for (int ksub = 0; ksub < 2; ++ksub) {
      int cA = ksub * 4 + (lane >> 4);
      short8 af[4], bf[4];
#pragma unroll
      for (int f = 0; f < 4; ++f) {
        int R = wr + f * 16 + fr;
        af[f] = *(const short8*)&As[R][(cA ^ (R & 7)) << 3];
        int Rb = wc + f * 16 + fr;
        bf[f] = *(const short8*)&Bs[Rb][(cA ^ (Rb & 7)) << 3];
      }
#pragma unroll
      for (int fi = 0; fi < 4; ++fi)
#pragma unroll
        for (int fj = 0; fj < 4; ++fj)
          acc[fi][fj] = __builtin_amdgcn_mfma_f32_16x16x32_bf16(af[fi], bf[fj], acc[fi][fj], 0, 0, 0);
    }
  }

  int orow = (lane >> 4) * 4;
  int ocol = lane & 15;
#pragma unroll
  for (int fi = 0; fi < 4; ++fi)
#pragma unroll
    for (int fj = 0; fj < 4; ++fj)
#pragma unroll
      for (int r = 0; r < 4; ++r) {
        size_t idx = (size_t)b * cStride +
                     (size_t)(bi + wr + fi * 16 + orow + r) * ldc +
                     (size_t)(bj + wc + fj * 16 + ocol);
        Cout[idx] = f2bf(acc[fi][fj][r]);
      }
}

// ---------- symmetric gram GEMM: S = xt . xt^T  (per batch).
// Only tiles byi<=bxi are computed (136/256); off-diagonal tiles are written
// twice: direct (register scalar stores) + mirrored (LDS col-major staging ->
// coalesced ushort8 stores). Values bit-identical => S exactly symmetric.
__global__ __launch_bounds__(256) void k_gram(const short* __restrict__ A,
                                              unsigned short* __restrict__ Cout,
                                              size_t aStride, size_t cStride, int ldc) {
  __shared__ short lds[16896];           // As/Bs (16384) or ep[128][132]
  short (*As)[64] = (short(*)[64])lds;
  short (*Bs)[64] = (short(*)[64])(lds + 8192);
  int lin = blockIdx.x;
  int b = lin & 7;                       // batch -> XCD
  int rest = lin >> 3;                   // 0..135 triangular index
  int byi = 0;
  while (rest >= 16 - byi) { rest -= 16 - byi; ++byi; }
  int bxi = byi + rest;
  const short* Ab = A + (size_t)b * aStride;
  int bi = byi * 128, bj = bxi * 128;
  int t = threadIdx.x, lane = t & 63, wid = t >> 6;
  int wr = (wid >> 1) * 64, wc = (wid & 1) * 64;
  int fr = lane & 15;
  int wbase = wid * 512;

  f32x4 acc[4][4];
  f32x4 z = {0.f, 0.f, 0.f, 0.f};
#pragma unroll
  for (int i = 0; i < 4; ++i)
#pragma unroll
    for (int j = 0; j < 4; ++j) acc[i][j] = z;

  for (int c0 = 0; c0 < C_; c0 += 64) {
    if (c0) __syncthreads();
#pragma unroll
    for (int i = 0; i < 4; ++i) {
      int li = i * 256 + t;
      int row = li >> 3, ch = li & 7;
      int sw = ((ch ^ (row & 7)) << 3);
      gload16(Ab + (size_t)(bi + row) * C_ + c0 + sw, lds + i * 2048 + wbase);
      gload16(Ab + (size_t)(bj + row) * C_ + c0 + sw, lds + 8192 + i * 2048 + wbase);
    }
    __syncthreads();
#pragma unroll
    for (int ksub = 0; ksub < 2; ++ksub) {
      int cA = ksub * 4 + (lane >> 4);
      short8 af[4], bf[4];
#pragma unroll
      for (int f = 0; f < 4; ++f) {
        int R = wr + f * 16 + fr;
        af[f] = *(const short8*)&As[R][(cA ^ (R & 7)) << 3];
        int Rb = wc + f * 16 + fr;
        bf[f] = *(const short8*)&Bs[Rb][(cA ^ (Rb & 7)) << 3];
      }
#pragma unroll
      for (int fi = 0; fi < 4; ++fi)
#pragma unroll
        for (int fj = 0; fj < 4; ++fj)
          acc[fi][fj] = __builtin_amdgcn_mfma_f32_16x16x32_bf16(af[fi], bf[fj], acc[fi][fj], 0, 0, 0);
    }
  }

  int orow = (lane >> 4) * 4;
  int ocol = lane & 15;
  unsigned short* Sb = Cout + (size_t)b * cStride;

  // direct tile write (as before)
#pragma unroll
  for (int fi = 0; fi < 4; ++fi)
#pragma unroll
    for (int fj = 0; fj < 4; ++fj)
#pragma unroll
      for (int r = 0; r < 4; ++r)
        Sb[(size_t)(bi + wr + fi * 16 + orow + r) * ldc +
           (bj + wc + fj * 16 + ocol)] = f2bf(acc[fi][fj][r]);

  if (bxi != byi) {                      // block-uniform branch
    __syncthreads();                     // all LDS fragment reads finished
    // stage col-major: ep[col][row], row-dim padded to 132 (264B, 8B-aligned)
    short* ep = lds;
#pragma unroll
    for (int fi = 0; fi < 4; ++fi)
#pragma unroll
      for (int fj = 0; fj < 4; ++fj) {
        int col = wc + fj * 16 + ocol;
        int row0 = wr + fi * 16 + orow;
        unsigned lo = (unsigned)f2bf(acc[fi][fj][0]) | ((unsigned)f2bf(acc[fi][fj][1]) << 16);
        unsigned hi = (unsigned)f2bf(acc[fi][fj][2]) | ((unsigned)f2bf(acc[fi][fj][3]) << 16);
        unsigned* p = (unsigned*)&ep[col * 132 + row0];
        p[0] = lo; p[1] = hi;
      }
    __syncthreads();
    // mirror write: S[bj+oc][bi + q*8 ..] with coalesced 16B stores
#pragma unroll
    for (int i2 = 0; i2 < 8; ++i2) {
      int id = i2 * 256 + t;
      int oc = id >> 4, q = id & 15;
      ushort8 v8 = *(const ushort8*)&ep[oc * 132 + q * 8];
      *(ushort8*)&Sb[(size_t)(bj + oc) * ldc + bi + q * 8] = v8;
    }
  }
}

// ---------- softmax + exact(bf16-granularity) top-k threshold + mask, one WAVE
// per row; batch->XCD pinned.
__global__ __launch_bounds__(256) void k_softmax_topk(unsigned short* __restrict__ S) {
  int t = threadIdx.x;
  int lane = t & 63, wv = t >> 6;
  int lin = blockIdx.x;
  int b = lin & 7;
  int grp = lin >> 3;
  size_t row = (size_t)b * N_ + grp * 4 + wv;
  unsigned short* sr = S + row * N_;

  float e[32];
#pragma unroll
  for (int i = 0; i < 4; ++i) {
    ushort8 raw = *(const ushort8*)(sr + ((size_t)(i * 64 + lane)) * 8);
#pragma unroll
    for (int j = 0; j < 8; ++j) e[i * 8 + j] = bf2f(raw[j]);
  }

  float lm = e[0];
#pragma unroll
  for (int j = 1; j < 32; ++j) lm = fmaxf(lm, e[j]);
#pragma unroll
  for (int m = 1; m <= 16; m <<= 1) lm = fmaxf(lm, __shfl_xor(lm, m));
  lm = fmaxf(__shfl(lm, 0), __shfl(lm, 32));

  float ls = 0.f;
#pragma unroll
  for (int j = 0; j < 32; ++j) { e[j] = __expf(e[j] - lm); ls += e[j]; }
#pragma unroll
  for (int m = 1; m <= 16; m <<= 1) ls += __shfl_xor(ls, m);
  ls = __shfl(ls, 0) + __shfl(ls, 32);
  float inv = 1.0f / ls;

  unsigned kp[16], vo[16];
#pragma unroll
  for (int q = 0; q < 16; ++q)
    kp[q] = (unsigned)f2bf(e[q]) | ((unsigned)f2bf(e[q + 16]) << 16);
#pragma unroll
  for (int q = 0; q < 16; ++q)
    vo[q] = (unsigned)f2bf(e[2 * q] * inv) | ((unsigned)f2bf(e[2 * q + 1] * inv) << 16);

  unsigned tp[16];
#pragma unroll
  for (int q = 0; q < 16; ++q) tp[q] = kp[q];
#pragma unroll
  for (int sI = 0; sI < 4; ++sI) {
    const int s = 8 >> sI;
    const unsigned msk = (s == 8) ? 0x00FF00FFu : (s == 4) ? 0x0F0F0F0Fu
                       : (s == 2) ? 0x33333333u : 0x55555555u;
#pragma unroll
    for (int k = 0; k < 16; ++k) {
      if ((k & s) == 0) {
        unsigned tt = ((tp[k] >> s) ^ tp[k + s]) & msk;
        tp[k + s] ^= tt;
        tp[k]     ^= tt << s;
      }
    }
  }

  unsigned alive = 0xFFFFFFFFu, prefix = 0u;
  int need = KKEEP;
#pragma unroll
  for (int b2 = 12; b2 >= 0; b2 -= 2) {
    unsigned p1 = tp[b2 + 1], p0 = tp[b2];
    unsigned hi = alive & p1;
    unsigned m3 = hi & p0, m2 = hi & ~p0, m1v = (alive & ~p1) & p0;
    unsigned packed = (unsigned)__popc(m3) | ((unsigned)__popc(m2) << 11) |
                      ((unsigned)__popc(m1v) << 22);
#pragma unroll
    for (int m = 1; m <= 16; m <<= 1) packed += __shfl_xor(packed, m);
    unsigned v0 = __shfl(packed, 0), v32 = __shfl(packed, 32);
    int C3 = (int)((v0 & 0x7FFu) + (v32 & 0x7FFu));
    int C2 = (int)(((v0 >> 11) & 0x7FFu) + ((v32 >> 11) & 0x7FFu));
    int C1 = (int)(((v0 >> 22) & 0x7FFu) + ((v32 >> 22) & 0x7FFu));
    int cum2 = C3 + C2, cum1 = cum2 + C1;
    if (C3 >= need)        { alive = m3;  prefix |= 3u << b2; }
    else if (cum2 >= need) { alive = m2;  prefix |= 2u << b2; need -= C3; }
    else if (cum1 >= need) { alive = m1v; prefix |= 1u << b2; need -= cum2; }
    else                   { alive ^= (m3 | m2 | m1v);        need -= cum1; }
  }

#pragma unroll
  for (int i = 0; i < 4; ++i) {
    ushort8 o;
#pragma unroll
    for (int j = 0; j < 8; ++j) {
      int idx = i * 8 + j;
      unsigned key = (kp[idx & 15] >> ((idx >> 4) * 16)) & 0xFFFFu;
      unsigned val = (vo[idx >> 1] >> ((idx & 1) * 16)) & 0xFFFFu;
      o[j] = (key >= prefix) ? (unsigned short)val : (unsigned short)0;
    }
    *(ushort8*)(sr + ((size_t)(i * 64 + lane)) * 8) = o;
  }
}

// ---------- PV GEMM (r9-proven): pre(n,d) = P . supT^T, 128x64 tile, BK=64,
// 4 waves, gload_lds + XOR swizzle; leaky + bf16 out + fused BN partials.
__global__ __launch_bounds__(256) void k_pv(const short* __restrict__ A,
                                            const short* __restrict__ Bt,
                                            unsigned short* __restrict__ pre,
                                            float* __restrict__ ps, float* __restrict__ pss) {
  __shared__ short As[128][64];
  __shared__ short Bs[64][64];
  int lin = blockIdx.x;
  int b = lin & 7;
  int rest = lin >> 3;
  int bxi = rest & 3;
  int byi = rest >> 2;
  const short* Ab = A + (size_t)b * N_ * N_;
  const short* Bb = Bt + (size_t)b * D_ * N_;
  int bi = byi * 128, bj = bxi * 64;
  int t = threadIdx.x, lane = t & 63, wid = t >> 6;
  int wr = wid * 32;
  int fr = lane & 15;
  int wbase = wid * 512;

  f32x4 acc[2][4];
  f32x4 z = {0.f, 0.f, 0.f, 0.f};
#pragma unroll
  for (int i = 0; i < 2; ++i)
#pragma unroll
    for (int j = 0; j < 4; ++j) acc[i][j] = z;

  for (int c0 = 0; c0 < N_; c0 += 64) {
    if (c0) __syncthreads();
#pragma unroll
    for (int i = 0; i < 4; ++i) {
      int li = i * 256 + t;
      int row = li >> 3, ch = li & 7;
      int sw = ((ch ^ (row & 7)) << 3);
      gload16(Ab + (size_t)(bi + row) * N_ + c0 + sw, (short*)As + i * 2048 + wbase);
      if (i < 2)
        gload16(Bb + (size_t)(bj + row) * N_ + c0 + sw, (short*)Bs + i * 2048 + wbase);
    }
    __syncthreads();
#pragma unroll
    for (int ksub = 0; ksub < 2; ++ksub) {
      int cA = ksub * 4 + (lane >> 4);
      short8 af[2], bf[4];
#pragma unroll
      for (int f = 0; f < 2; ++f) {
        int R = wr + f * 16 + fr;
        af[f] = *(const short8*)&As[R][(cA ^ (R & 7)) << 3];
      }
#pragma unroll
      for (int f = 0; f < 4; ++f) {
        int Rb = f * 16 + fr;
        bf[f] = *(const short8*)&Bs[Rb][(cA ^ (Rb & 7)) << 3];
      }
#pragma unroll
      for (int fi = 0; fi < 2; ++fi)
#pragma unroll
        for (int fj = 0; fj < 4; ++fj)
          acc[fi][fj] = __builtin_amdgcn_mfma_f32_16x16x32_bf16(af[fi], bf[fj], acc[fi][fj], 0, 0, 0);
    }
  }

  int orow = (lane >> 4) * 4;
  int ocol = lane & 15;
  float s4[4] = {0.f, 0.f, 0.f, 0.f}, ss4[4] = {0.f, 0.f, 0.f, 0.f};
#pragma unroll
  for (int fi = 0; fi < 2; ++fi)
#pragma unroll
    for (int rr = 0; rr < 4; ++rr) {
      int rowg = bi + wr + fi * 16 + orow + rr;
      size_t base = ((size_t)b * N_ + rowg) * D_ + bj;
#pragma unroll
      for (int fj = 0; fj < 4; ++fj) {
        float v = acc[fi][fj][rr];
        v = (v >= 0.f) ? v : LEAKY * v;
        pre[base + fj * 16 + ocol] = f2bf(v);
        s4[fj] += v;
        ss4[fj] = fmaf(v, v, ss4[fj]);
      }
    }
#pragma unroll
  for (int fj = 0; fj < 4; ++fj) {
    s4[fj] += __shfl_xor(s4[fj], 16);  s4[fj] += __shfl_xor(s4[fj], 32);
    ss4[fj] += __shfl_xor(ss4[fj], 16); ss4[fj] += __shfl_xor(ss4[fj], 32);
  }
  __syncthreads();
  float* sred = (float*)As;
  if (lane < 16) {
#pragma unroll
    for (int fj = 0; fj < 4; ++fj) {
      sred[(wid * 4 + fj) * 16 + lane] = s4[fj];
      sred[256 + (wid * 4 + fj) * 16 + lane] = ss4[fj];
    }
  }
  __syncthreads();
  if (t < 64) {
    float s = 0.f, ss = 0.f;
#pragma unroll
    for (int w4 = 0; w4 < 4; ++w4) {
      s  += sred[(w4 * 4 + (t >> 4)) * 16 + (t & 15)];
      ss += sred[256 + (w4 * 4 + (t >> 4)) * 16 + (t & 15)];
    }
    ps[(size_t)lin * 64 + t] = s;
    pss[(size_t)lin * 64 + t] = ss;
  }
}

// ---------- BN finalize: 4 blocks x 64 channels
__global__ void k_final(const float* __restrict__ ps, const float* __restrict__ pss,
                        const float* __restrict__ bnw, const float* __restrict__ bnb,
                        float* __restrict__ scale, float* __restrict__ shift) {
  int col = threadIdx.x;
  int bxi = blockIdx.x;
  int ch = bxi * 64 + col;
  float s = 0.f, ss = 0.f;
  for (int byi = 0; byi < 16; ++byi)
    for (int bb = 0; bb < 8; ++bb) {
      int lin = (byi * 4 + bxi) * 8 + bb;
      s += ps[(size_t)lin * 64 + col];
      ss += pss[(size_t)lin * 64 + col];
    }
  const float invN = 1.0f / (B_ * N_);
  float mean = s * invN;
  float var = fmaf(-mean, mean, ss * invN);
  float istd = rsqrtf(var + EPS);
  float sc = istd * bnw[ch];
  scale[ch] = sc;
  shift[ch] = fmaf(-mean, sc, bnb[ch]);
}

// ---------- normalize + transpose (b,n,d) bf16 -> (b,d,n) f32; batch-pinned
__global__ __launch_bounds__(256) void k_out(const unsigned short* __restrict__ pre,
                                             const float* __restrict__ scale,
                                             const float* __restrict__ shift,
                                             float* __restrict__ out) {
  __shared__ float tile[32][33];
  int lin = blockIdx.x;
  int b = lin & 7;
  int rest = lin >> 3;
  int d0 = (rest & 7) * 32;
  int n0 = (rest >> 3) * 32;
  int tc = threadIdx.x & 31;
  int tr = threadIdx.x >> 5;
  const unsigned short* pb = pre + ((size_t)b * N_ + n0) * D_ + d0;
#pragma unroll
  for (int i = 0; i < 4; ++i) {
    int r = tr + i * 8;
    tile[r][tc] = bf2f(pb[(size_t)r * D_ + tc]);
  }
  __syncthreads();
  float* ob = out + ((size_t)b * D_ + d0) * N_ + n0;
#pragma unroll
  for (int i = 0; i < 4; ++i) {
    int r = tr + i * 8;
    float vv = tile[tc][r];
    ob[(size_t)r * N_ + tc] = fmaf(vv, scale[d0 + r], shift[d0 + r]);
  }
}

extern "C" void kernel_launch(void* const* d_in, const int* in_sizes, int n_in,
                              void* d_out, int out_size, void* d_ws, size_t ws_size,
                              hipStream_t stream) {
  const float* x = (const float*)d_in[0];
  const float* W = (const float*)d_in[1];
  const float* bnw = (const float*)d_in[2];
  const float* bnb = (const float*)d_in[3];
  float* out = (float*)d_out;

  char* w = (char*)d_ws;
  short* xt = (short*)w;            w += (size_t)B_ * N_ * C_ * 2;     // (b,n,c) bf16
  short* wt = (short*)w;            w += (size_t)D_ * C_ * 2;          // (d,c) bf16
  short* supT = (short*)w;          w += (size_t)B_ * D_ * N_ * 2;     // (b,d,m) bf16
  short* S = (short*)w;             w += (size_t)B_ * N_ * N_ * 2;     // (b,n,m) bf16
  unsigned short* pre = (unsigned short*)w; w += (size_t)B_ * N_ * D_ * 2; // (b,n,d) bf16
  float* ps = (float*)w;            w += (size_t)512 * 64 * 4;         // stat partials
  float* pss = (float*)w;           w += (size_t)512 * 64 * 4;
  float* scale = (float*)w;         w += D_ * 4;
  float* shift = (float*)w;         w += D_ * 4;

  // 1. layout prep
  k_transpose_cast<true><<<dim3(8 * 64 * 8, 1, 1), 256, 0, stream>>>(
      x, (unsigned short*)xt, C_, N_, 64, (size_t)C_ * N_, (size_t)N_ * C_);
  k_transpose_cast<false><<<dim3(D_ / 32, C_ / 32, 1), 256, 0, stream>>>(
      W, (unsigned short*)wt, C_, D_, 0, 0, 0);

  // 2. supT(d,m) = wt . xt^T — 256 blocks, batch->XCD pinned
  k_gemm<C_, 16><<<dim3(8 * 16 * 2, 1, 1), 256, 0, stream>>>(
      wt, xt, (unsigned short*)supT, 0, (size_t)N_ * C_, (size_t)D_ * N_, N_);

  // 3. S(n,m) = xt . xt^T — symmetric: 136 tiles/batch, 1088 blocks
  k_gram<<<dim3(8 * 136, 1, 1), 256, 0, stream>>>(
      xt, (unsigned short*)S, (size_t)N_ * C_, (size_t)N_ * N_, N_);

  // 4. softmax + topk mask (in place), one wave per row, batch->XCD pinned
  k_softmax_topk<<<B_ * N_ / 4, 256, 0, stream>>>((unsigned short*)S);

  // 5. PV (BK=64, gload_lds, 4 waves), leaky + bf16 out + fused BN partials
  k_pv<<<dim3(4 * 16 * 8, 1, 1), 256, 0, stream>>>(S, supT, pre, ps, pss);

  // 6. finalize BN + output
  k_final<<<4, 64, 0, stream>>>(ps, pss, bnw, bnb, scale, shift);
  k_out<<<B_ * (N_ / 32) * (D_ / 32), 256, 0, stream>>>(pre, scale, shift, out);
}